// Round 1
// baseline (3962.921 us; speedup 1.0000x reference)
//
#include <hip/hip_runtime.h>
#include <math.h>

#define BB 4
#define TT 2048
#define DD 1024
#define HH 128
#define EPSF 1e-6f
#define BT (BB*TT)   // 8192

// ---------------------------------------------------------------------------
// Projection: P[bt][h] = sum_d x[bt][d] * W[h][d] + bias[h]
// gridDim.x = BT/64, gridDim.y = 3 (q,k,v). block = 256.
// 64(t) x 128(h) tile, k-tiles of 32, transposed LDS staging, 4x8 micro-tile.
// ---------------------------------------------------------------------------
__global__ __launch_bounds__(256) void proj_kernel(
    const float* __restrict__ x,
    const float* __restrict__ Wq, const float* __restrict__ bq,
    const float* __restrict__ Wk, const float* __restrict__ bk,
    const float* __restrict__ Wv, const float* __restrict__ bv,
    float* __restrict__ Q, float* __restrict__ K, float* __restrict__ V)
{
    const int which = blockIdx.y;
    const float* W    = (which == 0) ? Wq : (which == 1) ? Wk : Wv;
    const float* bias = (which == 0) ? bq : (which == 1) ? bk : bv;
    float* P          = (which == 0) ? Q  : (which == 1) ? K  : V;

    const int row0 = blockIdx.x * 64;

    __shared__ float xT[32][68];    // xT[kk][r], padded row (16B-aligned rows)
    __shared__ float wT[32][132];   // wT[kk][h]

    const int tid = threadIdx.x;
    const int tx = tid & 15;        // h group: cols tx*8 .. tx*8+7
    const int ty = tid >> 4;        // t group: rows ty*4 .. ty*4+3

    float acc[4][8];
    #pragma unroll
    for (int i = 0; i < 4; i++)
        #pragma unroll
        for (int j = 0; j < 8; j++) acc[i][j] = 0.f;

    for (int k0 = 0; k0 < DD; k0 += 32) {
        // x tile 64x32 -> transposed
        #pragma unroll
        for (int l = 0; l < 2; l++) {
            int f = tid + l * 256;              // 0..511 float4 slots
            int r = f >> 3;
            int cg = f & 7;
            float4 v = *(const float4*)(x + (size_t)(row0 + r) * DD + k0 + cg * 4);
            xT[cg*4+0][r] = v.x; xT[cg*4+1][r] = v.y;
            xT[cg*4+2][r] = v.z; xT[cg*4+3][r] = v.w;
        }
        // W tile 128x32 -> transposed
        #pragma unroll
        for (int l = 0; l < 4; l++) {
            int f = tid + l * 256;              // 0..1023
            int h = f >> 3;
            int cg = f & 7;
            float4 v = *(const float4*)(W + (size_t)h * DD + k0 + cg * 4);
            wT[cg*4+0][h] = v.x; wT[cg*4+1][h] = v.y;
            wT[cg*4+2][h] = v.z; wT[cg*4+3][h] = v.w;
        }
        __syncthreads();
        #pragma unroll
        for (int kk = 0; kk < 32; kk++) {
            float4 xv = *(const float4*)&xT[kk][ty * 4];
            float4 w0 = *(const float4*)&wT[kk][tx * 8];
            float4 w1 = *(const float4*)&wT[kk][tx * 8 + 4];
            float xa[4] = {xv.x, xv.y, xv.z, xv.w};
            float wa[8] = {w0.x, w0.y, w0.z, w0.w, w1.x, w1.y, w1.z, w1.w};
            #pragma unroll
            for (int i = 0; i < 4; i++)
                #pragma unroll
                for (int j = 0; j < 8; j++)
                    acc[i][j] += xa[i] * wa[j];
        }
        __syncthreads();
    }

    #pragma unroll
    for (int i = 0; i < 4; i++) {
        int row = row0 + ty * 4 + i;
        #pragma unroll
        for (int j = 0; j < 8; j++) acc[i][j] += bias[tx * 8 + j];
        float4 o0 = {acc[i][0], acc[i][1], acc[i][2], acc[i][3]};
        float4 o1 = {acc[i][4], acc[i][5], acc[i][6], acc[i][7]};
        *(float4*)(P + (size_t)row * HH + tx * 8)     = o0;
        *(float4*)(P + (size_t)row * HH + tx * 8 + 4) = o1;
    }
}

// ---------------------------------------------------------------------------
// Sequential scan. grid = B blocks, block = 512 threads.
// Thread (quarter qd = tid>>7, row r = tid&127) owns A[r][qd*32..+31] and
// M[r][qd*32..+31] in registers. Broadcast vectors in LDS.
// ---------------------------------------------------------------------------
__global__ __launch_bounds__(512) void scan_kernel(
    const float* __restrict__ Q, const float* __restrict__ K,
    const float* __restrict__ V, float* __restrict__ O)
{
    const int b   = blockIdx.x;
    const int tid = threadIdx.x;
    const int r   = tid & 127;
    const int qd  = tid >> 7;
    const int c0  = qd * 32;
    const int lane = tid & 63;
    const int wave = tid >> 6;

    __shared__ float us[128], qs[128], vs[128], Aus[128];
    __shared__ float part[4][128];
    __shared__ float scal[2];   // [0]=1/denom, [1]=s/denom

    float Areg[32], Mreg[32];
    #pragma unroll
    for (int j = 0; j < 32; j++) {
        Mreg[j] = 0.f;
        Areg[j] = (c0 + j == r) ? 1.0f : 0.0f;   // A0 = I / lambda0, lambda0 = 1
    }

    const float* Qb = Q + (size_t)b * TT * HH;
    const float* Kb = K + (size_t)b * TT * HH;
    const float* Vb = V + (size_t)b * TT * HH;
    float*       Ob = O + (size_t)b * TT * HH;

    float s_reg = 0.f;   // valid in wave 0 only

    for (int t = 0; t < TT; t++) {
        // (a) wave 0: load q,k,v; reduce ||k||^2 and k.q; write u,q,v to LDS
        if (wave == 0) {
            float k0v = Kb[t * HH + lane];
            float k1v = Kb[t * HH + lane + 64];
            float q0v = Qb[t * HH + lane];
            float q1v = Qb[t * HH + lane + 64];
            float v0v = Vb[t * HH + lane];
            float v1v = Vb[t * HH + lane + 64];
            float pk2 = k0v * k0v + k1v * k1v;
            float pkq = k0v * q0v + k1v * q1v;
            #pragma unroll
            for (int off = 32; off; off >>= 1) {
                pk2 += __shfl_xor(pk2, off);
                pkq += __shfl_xor(pkq, off);
            }
            s_reg = pkq;
            float rn = 1.0f / (sqrtf(pk2) + EPSF);
            us[lane] = k0v * rn; us[lane + 64] = k1v * rn;
            qs[lane] = q0v;      qs[lane + 64] = q1v;
            vs[lane] = v0v;      vs[lane + 64] = v1v;
        }
        __syncthreads();

        // (b) matvec partials: part[qd][r] = sum_j A[r][c0+j] * u[c0+j]
        {
            float p = 0.f;
            #pragma unroll
            for (int j = 0; j < 32; j += 4) {
                float4 uv = *(const float4*)&us[c0 + j];
                p += Areg[j]   * uv.x + Areg[j+1] * uv.y
                   + Areg[j+2] * uv.z + Areg[j+3] * uv.w;
            }
            part[qd][r] = p;
        }
        __syncthreads();

        // (c) wave 0: reduce Au, compute denom
        if (wave == 0) {
            float au0 = part[0][lane] + part[1][lane] + part[2][lane] + part[3][lane];
            float au1 = part[0][lane+64] + part[1][lane+64] + part[2][lane+64] + part[3][lane+64];
            Aus[lane] = au0; Aus[lane + 64] = au1;
            float pd = us[lane] * au0 + us[lane + 64] * au1;
            #pragma unroll
            for (int off = 32; off; off >>= 1) pd += __shfl_xor(pd, off);
            float inv_d = 1.0f / (1.0f + pd);
            if (lane == 0) { scal[0] = inv_d; scal[1] = s_reg * inv_d; }
        }
        __syncthreads();

        // (d) update A (rank-1), update M (rank-1), accumulate o partial
        {
            float inv_d = scal[0];
            float sa    = scal[1];
            float cA = Aus[r] * inv_d;
            float cM = vs[r] * sa;
            float op = 0.f;
            #pragma unroll
            for (int j = 0; j < 32; j += 4) {
                float4 av = *(const float4*)&Aus[c0 + j];
                float4 qv = *(const float4*)&qs[c0 + j];
                float aj[4] = {av.x, av.y, av.z, av.w};
                float qj[4] = {qv.x, qv.y, qv.z, qv.w};
                #pragma unroll
                for (int jj = 0; jj < 4; jj++) {
                    Areg[j + jj] -= cA * aj[jj];
                    Mreg[j + jj] += cM * aj[jj];
                    op += Mreg[j + jj] * qj[jj];
                }
            }
            part[qd][r] = op;
        }
        __syncthreads();

        // (e) wave 0: reduce o, store to global. Safe vs next (a): waves 1..7
        // wait at the (a)-end barrier until wave 0 finishes (e)+(a).
        if (wave == 0) {
            float o0 = part[0][lane] + part[1][lane] + part[2][lane] + part[3][lane];
            float o1 = part[0][lane+64] + part[1][lane+64] + part[2][lane+64] + part[3][lane+64];
            Ob[t * HH + lane]      = o0;
            Ob[t * HH + lane + 64] = o1;
        }
    }
}

// ---------------------------------------------------------------------------
// Output: out[bt][d] = sum_h O[bt][h] * Wo[d][h] + bo[d]
// grid (BT/64, DD/128), block 256. Same tiling as proj.
// ---------------------------------------------------------------------------
__global__ __launch_bounds__(256) void out_kernel(
    const float* __restrict__ O, const float* __restrict__ Wo,
    const float* __restrict__ bo, float* __restrict__ out)
{
    const int row0 = blockIdx.x * 64;
    const int d0   = blockIdx.y * 128;

    __shared__ float oT[32][68];     // oT[kk][r]
    __shared__ float woT[32][132];   // woT[kk][d]

    const int tid = threadIdx.x;
    const int tx = tid & 15;
    const int ty = tid >> 4;

    float acc[4][8];
    #pragma unroll
    for (int i = 0; i < 4; i++)
        #pragma unroll
        for (int j = 0; j < 8; j++) acc[i][j] = 0.f;

    for (int k0 = 0; k0 < HH; k0 += 32) {
        #pragma unroll
        for (int l = 0; l < 2; l++) {
            int f = tid + l * 256;
            int r = f >> 3;
            int cg = f & 7;
            float4 v = *(const float4*)(O + (size_t)(row0 + r) * HH + k0 + cg * 4);
            oT[cg*4+0][r] = v.x; oT[cg*4+1][r] = v.y;
            oT[cg*4+2][r] = v.z; oT[cg*4+3][r] = v.w;
        }
        #pragma unroll
        for (int l = 0; l < 4; l++) {
            int f = tid + l * 256;
            int d = f >> 3;
            int cg = f & 7;
            float4 v = *(const float4*)(Wo + (size_t)(d0 + d) * HH + k0 + cg * 4);
            woT[cg*4+0][d] = v.x; woT[cg*4+1][d] = v.y;
            woT[cg*4+2][d] = v.z; woT[cg*4+3][d] = v.w;
        }
        __syncthreads();
        #pragma unroll
        for (int kk = 0; kk < 32; kk++) {
            float4 ov = *(const float4*)&oT[kk][ty * 4];
            float4 w0 = *(const float4*)&woT[kk][tx * 8];
            float4 w1 = *(const float4*)&woT[kk][tx * 8 + 4];
            float oa[4] = {ov.x, ov.y, ov.z, ov.w};
            float wa[8] = {w0.x, w0.y, w0.z, w0.w, w1.x, w1.y, w1.z, w1.w};
            #pragma unroll
            for (int i = 0; i < 4; i++)
                #pragma unroll
                for (int j = 0; j < 8; j++)
                    acc[i][j] += oa[i] * wa[j];
        }
        __syncthreads();
    }

    #pragma unroll
    for (int i = 0; i < 4; i++) {
        int row = row0 + ty * 4 + i;
        #pragma unroll
        for (int j = 0; j < 8; j++) acc[i][j] += bo[d0 + tx * 8 + j];
        float4 o0 = {acc[i][0], acc[i][1], acc[i][2], acc[i][3]};
        float4 o1 = {acc[i][4], acc[i][5], acc[i][6], acc[i][7]};
        *(float4*)(out + (size_t)row * DD + d0 + tx * 8)     = o0;
        *(float4*)(out + (size_t)row * DD + d0 + tx * 8 + 4) = o1;
    }
}

extern "C" void kernel_launch(void* const* d_in, const int* in_sizes, int n_in,
                              void* d_out, int out_size, void* d_ws, size_t ws_size,
                              hipStream_t stream) {
    const float* x  = (const float*)d_in[0];
    const float* Wq = (const float*)d_in[1];
    const float* bq = (const float*)d_in[2];
    const float* Wk = (const float*)d_in[3];
    const float* bk = (const float*)d_in[4];
    const float* Wv = (const float*)d_in[5];
    const float* bv = (const float*)d_in[6];
    const float* Wo = (const float*)d_in[7];
    const float* bo = (const float*)d_in[8];
    float* out = (float*)d_out;

    float* ws = (float*)d_ws;
    float* Q = ws;                       // BT*HH each
    float* K = ws + (size_t)BT * HH;
    float* V = ws + (size_t)2 * BT * HH;
    float* O = ws + (size_t)3 * BT * HH;

    dim3 pgrid(BT / 64, 3);
    proj_kernel<<<pgrid, 256, 0, stream>>>(x, Wq, bq, Wk, bk, Wv, bv, Q, K, V);

    scan_kernel<<<BB, 512, 0, stream>>>(Q, K, V, O);

    dim3 ogrid(BT / 64, DD / 128);
    out_kernel<<<ogrid, 256, 0, stream>>>(O, Wo, bo, out);
}

// Round 2
// 3478.893 us; speedup vs baseline: 1.1391x; 1.1391x over previous
//
#include <hip/hip_runtime.h>
#include <math.h>

#define BB 4
#define TT 2048
#define DD 1024
#define HH 128
#define EPSF 1e-6f
#define BT (BB*TT)   // 8192

// ---------------------------------------------------------------------------
// Projection: P[bt][h] = sum_d x[bt][d] * W[h][d] + bias[h]
// gridDim.x = BT/64, gridDim.y = 3 (q,k,v). block = 256.
// ---------------------------------------------------------------------------
__global__ __launch_bounds__(256) void proj_kernel(
    const float* __restrict__ x,
    const float* __restrict__ Wq, const float* __restrict__ bq,
    const float* __restrict__ Wk, const float* __restrict__ bk,
    const float* __restrict__ Wv, const float* __restrict__ bv,
    float* __restrict__ Q, float* __restrict__ K, float* __restrict__ V)
{
    const int which = blockIdx.y;
    const float* W    = (which == 0) ? Wq : (which == 1) ? Wk : Wv;
    const float* bias = (which == 0) ? bq : (which == 1) ? bk : bv;
    float* P          = (which == 0) ? Q  : (which == 1) ? K  : V;

    const int row0 = blockIdx.x * 64;

    __shared__ float xT[32][68];
    __shared__ float wT[32][132];

    const int tid = threadIdx.x;
    const int tx = tid & 15;
    const int ty = tid >> 4;

    float acc[4][8];
    #pragma unroll
    for (int i = 0; i < 4; i++)
        #pragma unroll
        for (int j = 0; j < 8; j++) acc[i][j] = 0.f;

    for (int k0 = 0; k0 < DD; k0 += 32) {
        #pragma unroll
        for (int l = 0; l < 2; l++) {
            int f = tid + l * 256;
            int r = f >> 3;
            int cg = f & 7;
            float4 v = *(const float4*)(x + (size_t)(row0 + r) * DD + k0 + cg * 4);
            xT[cg*4+0][r] = v.x; xT[cg*4+1][r] = v.y;
            xT[cg*4+2][r] = v.z; xT[cg*4+3][r] = v.w;
        }
        #pragma unroll
        for (int l = 0; l < 4; l++) {
            int f = tid + l * 256;
            int h = f >> 3;
            int cg = f & 7;
            float4 v = *(const float4*)(W + (size_t)h * DD + k0 + cg * 4);
            wT[cg*4+0][h] = v.x; wT[cg*4+1][h] = v.y;
            wT[cg*4+2][h] = v.z; wT[cg*4+3][h] = v.w;
        }
        __syncthreads();
        #pragma unroll
        for (int kk = 0; kk < 32; kk++) {
            float4 xv = *(const float4*)&xT[kk][ty * 4];
            float4 w0 = *(const float4*)&wT[kk][tx * 8];
            float4 w1 = *(const float4*)&wT[kk][tx * 8 + 4];
            float xa[4] = {xv.x, xv.y, xv.z, xv.w};
            float wa[8] = {w0.x, w0.y, w0.z, w0.w, w1.x, w1.y, w1.z, w1.w};
            #pragma unroll
            for (int i = 0; i < 4; i++)
                #pragma unroll
                for (int j = 0; j < 8; j++)
                    acc[i][j] += xa[i] * wa[j];
        }
        __syncthreads();
    }

    #pragma unroll
    for (int i = 0; i < 4; i++) {
        int row = row0 + ty * 4 + i;
        #pragma unroll
        for (int j = 0; j < 8; j++) acc[i][j] += bias[tx * 8 + j];
        float4 o0 = {acc[i][0], acc[i][1], acc[i][2], acc[i][3]};
        float4 o1 = {acc[i][4], acc[i][5], acc[i][6], acc[i][7]};
        *(float4*)(P + (size_t)row * HH + tx * 8)     = o0;
        *(float4*)(P + (size_t)row * HH + tx * 8 + 4) = o1;
    }
}

// ---------------------------------------------------------------------------
// Sequential scan, latency-optimized. grid = B blocks, block = 512 threads.
// Thread owns A[r][c0..c0+31], M[r][c0..c0+31] in registers, where
// r = tid>>2, c0 = (tid&3)*32. Row quad = 4 consecutive lanes -> shfl reduce.
// 2 barriers/step; broadcast LDS double-buffered; q/k/v prefetched.
// ---------------------------------------------------------------------------
__global__ __launch_bounds__(512) void scan_kernel(
    const float* __restrict__ Q, const float* __restrict__ K,
    const float* __restrict__ V, float* __restrict__ O)
{
    const int b    = blockIdx.x;
    const int tid  = threadIdx.x;
    const int r    = tid >> 2;     // row 0..127
    const int q4   = tid & 3;      // column quarter
    const int c0   = q4 * 32;
    const int lane = tid & 63;
    const int wave = tid >> 6;

    __shared__ float us[2][128], qs[2][128], vs[2][128], Aus[2][128];
    __shared__ float dwave[2][8];
    __shared__ float ss[2];

    float Areg[32], Mreg[32];
    #pragma unroll
    for (int j = 0; j < 32; j++) {
        Mreg[j] = 0.f;
        Areg[j] = (c0 + j == r) ? 1.0f : 0.0f;   // A0 = I / lambda0
    }

    const float* Qb = Q + (size_t)b * TT * HH;
    const float* Kb = K + (size_t)b * TT * HH;
    const float* Vb = V + (size_t)b * TT * HH;
    float*       Ob = O + (size_t)b * TT * HH;

    // prefetch t=0 (wave 0 only)
    float pk0 = 0.f, pk1 = 0.f, pq0 = 0.f, pq1 = 0.f, pv0 = 0.f, pv1 = 0.f;
    if (wave == 0) {
        pk0 = Kb[lane]; pk1 = Kb[lane + 64];
        pq0 = Qb[lane]; pq1 = Qb[lane + 64];
        pv0 = Vb[lane]; pv1 = Vb[lane + 64];
    }

    for (int t = 0; t < TT; t++) {
        const int buf = t & 1;

        // --- phase 1 (wave 0): normalize k -> u, k.q, broadcast; prefetch t+1
        if (wave == 0) {
            float k0v = pk0, k1v = pk1;
            float q0v = pq0, q1v = pq1;
            float v0v = pv0, v1v = pv1;
            float pk2 = k0v * k0v + k1v * k1v;
            float pkq = k0v * q0v + k1v * q1v;
            #pragma unroll
            for (int off = 32; off; off >>= 1) {
                pk2 += __shfl_xor(pk2, off);
                pkq += __shfl_xor(pkq, off);
            }
            float rn = 1.0f / (sqrtf(pk2) + EPSF);
            us[buf][lane] = k0v * rn; us[buf][lane + 64] = k1v * rn;
            qs[buf][lane] = q0v;      qs[buf][lane + 64] = q1v;
            vs[buf][lane] = v0v;      vs[buf][lane + 64] = v1v;
            if (lane == 0) ss[buf] = pkq;
            if (t + 1 < TT) {
                const int base = (t + 1) * HH + lane;
                pk0 = Kb[base]; pk1 = Kb[base + 64];
                pq0 = Qb[base]; pq1 = Qb[base + 64];
                pv0 = Vb[base]; pv1 = Vb[base + 64];
            }
        }
        __syncthreads();   // B1: us/qs/vs/ss[buf] ready

        // --- phase 2: Au[r] via quad-shuffle; denom partial per wave
        const float* ub = us[buf];
        float p = 0.f;
        #pragma unroll
        for (int j = 0; j < 32; j += 4) {
            float4 uv = *(const float4*)&ub[c0 + j];
            p += Areg[j]   * uv.x + Areg[j+1] * uv.y
               + Areg[j+2] * uv.z + Areg[j+3] * uv.w;
        }
        p += __shfl_xor(p, 1);
        p += __shfl_xor(p, 2);      // all 4 lanes of the quad hold Au[r]
        float dval = 0.f;
        if (q4 == 0) {
            Aus[buf][r] = p;
            dval = ub[r] * p;
        }
        #pragma unroll
        for (int off = 32; off; off >>= 1) dval += __shfl_xor(dval, off);
        if (lane == 0) dwave[buf][wave] = dval;
        __syncthreads();   // B2: Aus + dwave ready

        // --- phase 3 (all threads, redundant): denom, scalars
        float4 d0 = *(const float4*)&dwave[buf][0];
        float4 d1 = *(const float4*)&dwave[buf][4];
        float denom = 1.0f + d0.x + d0.y + d0.z + d0.w
                           + d1.x + d1.y + d1.z + d1.w;
        float inv_d = 1.0f / denom;
        float sa    = ss[buf] * inv_d;

        // --- phase 4: rank-1 updates + o partial
        float cA = p * inv_d;              // Au[r] * inv_d (in-register)
        float cM = vs[buf][r] * sa;
        const float* ab = Aus[buf];
        const float* qb = qs[buf];
        float o = 0.f;
        #pragma unroll
        for (int j = 0; j < 32; j += 4) {
            float4 av = *(const float4*)&ab[c0 + j];
            float4 qv = *(const float4*)&qb[c0 + j];
            Areg[j]   -= cA * av.x;  Mreg[j]   += cM * av.x;  o += Mreg[j]   * qv.x;
            Areg[j+1] -= cA * av.y;  Mreg[j+1] += cM * av.y;  o += Mreg[j+1] * qv.y;
            Areg[j+2] -= cA * av.z;  Mreg[j+2] += cM * av.z;  o += Mreg[j+2] * qv.z;
            Areg[j+3] -= cA * av.w;  Mreg[j+3] += cM * av.w;  o += Mreg[j+3] * qv.w;
        }
        o += __shfl_xor(o, 1);
        o += __shfl_xor(o, 2);
        if (q4 == 0) Ob[t * HH + r] = o;
        // No end barrier: next-iteration B1 orders phase-4 reads of buf
        // against the next step's writes, which all target buf^1.
    }
}

// ---------------------------------------------------------------------------
// Output: out[bt][d] = sum_h O[bt][h] * Wo[d][h] + bo[d]
// ---------------------------------------------------------------------------
__global__ __launch_bounds__(256) void out_kernel(
    const float* __restrict__ O, const float* __restrict__ Wo,
    const float* __restrict__ bo, float* __restrict__ out)
{
    const int row0 = blockIdx.x * 64;
    const int d0   = blockIdx.y * 128;

    __shared__ float oT[32][68];
    __shared__ float woT[32][132];

    const int tid = threadIdx.x;
    const int tx = tid & 15;
    const int ty = tid >> 4;

    float acc[4][8];
    #pragma unroll
    for (int i = 0; i < 4; i++)
        #pragma unroll
        for (int j = 0; j < 8; j++) acc[i][j] = 0.f;

    for (int k0 = 0; k0 < HH; k0 += 32) {
        #pragma unroll
        for (int l = 0; l < 2; l++) {
            int f = tid + l * 256;
            int r = f >> 3;
            int cg = f & 7;
            float4 v = *(const float4*)(O + (size_t)(row0 + r) * HH + k0 + cg * 4);
            oT[cg*4+0][r] = v.x; oT[cg*4+1][r] = v.y;
            oT[cg*4+2][r] = v.z; oT[cg*4+3][r] = v.w;
        }
        #pragma unroll
        for (int l = 0; l < 4; l++) {
            int f = tid + l * 256;
            int d = f >> 3;
            int cg = f & 7;
            float4 v = *(const float4*)(Wo + (size_t)(d0 + d) * HH + k0 + cg * 4);
            woT[cg*4+0][d] = v.x; woT[cg*4+1][d] = v.y;
            woT[cg*4+2][d] = v.z; woT[cg*4+3][d] = v.w;
        }
        __syncthreads();
        #pragma unroll
        for (int kk = 0; kk < 32; kk++) {
            float4 ov = *(const float4*)&oT[kk][ty * 4];
            float4 w0 = *(const float4*)&woT[kk][tx * 8];
            float4 w1 = *(const float4*)&woT[kk][tx * 8 + 4];
            float oa[4] = {ov.x, ov.y, ov.z, ov.w};
            float wa[8] = {w0.x, w0.y, w0.z, w0.w, w1.x, w1.y, w1.z, w1.w};
            #pragma unroll
            for (int i = 0; i < 4; i++)
                #pragma unroll
                for (int j = 0; j < 8; j++)
                    acc[i][j] += oa[i] * wa[j];
        }
        __syncthreads();
    }

    #pragma unroll
    for (int i = 0; i < 4; i++) {
        int row = row0 + ty * 4 + i;
        #pragma unroll
        for (int j = 0; j < 8; j++) acc[i][j] += bo[d0 + tx * 8 + j];
        float4 o0 = {acc[i][0], acc[i][1], acc[i][2], acc[i][3]};
        float4 o1 = {acc[i][4], acc[i][5], acc[i][6], acc[i][7]};
        *(float4*)(out + (size_t)row * DD + d0 + tx * 8)     = o0;
        *(float4*)(out + (size_t)row * DD + d0 + tx * 8 + 4) = o1;
    }
}

extern "C" void kernel_launch(void* const* d_in, const int* in_sizes, int n_in,
                              void* d_out, int out_size, void* d_ws, size_t ws_size,
                              hipStream_t stream) {
    const float* x  = (const float*)d_in[0];
    const float* Wq = (const float*)d_in[1];
    const float* bq = (const float*)d_in[2];
    const float* Wk = (const float*)d_in[3];
    const float* bk = (const float*)d_in[4];
    const float* Wv = (const float*)d_in[5];
    const float* bv = (const float*)d_in[6];
    const float* Wo = (const float*)d_in[7];
    const float* bo = (const float*)d_in[8];
    float* out = (float*)d_out;

    float* ws = (float*)d_ws;
    float* Q = ws;
    float* K = ws + (size_t)BT * HH;
    float* V = ws + (size_t)2 * BT * HH;
    float* O = ws + (size_t)3 * BT * HH;

    dim3 pgrid(BT / 64, 3);
    proj_kernel<<<pgrid, 256, 0, stream>>>(x, Wq, bq, Wk, bk, Wv, bv, Q, K, V);

    scan_kernel<<<BB, 512, 0, stream>>>(Q, K, V, O);

    dim3 ogrid(BT / 64, DD / 128);
    out_kernel<<<ogrid, 256, 0, stream>>>(O, Wo, bo, out);
}